// Round 3
// baseline (659.502 us; speedup 1.0000x reference)
//
#include <hip/hip_runtime.h>
#include <hip/hip_bf16.h>
#include <math.h>

#define NROWS 8192
#define DIM   1024
#define CAP   256
#define MARGIN 120.0f

using f16x8 = __attribute__((ext_vector_type(8))) _Float16;
using f32x4 = __attribute__((ext_vector_type(4))) float;
typedef unsigned short u16;
typedef unsigned int   u32;

#define AS1 __attribute__((address_space(1)))
#define AS3 __attribute__((address_space(3)))

// inline-asm LDS read: invisible to the compiler's LDS-alias waitcnt tracking
// (no auto vmcnt(0) drains). Ordering vs MFMA enforced by counted lgkmcnt +
// sched_barrier(0) (rule #18).
#define DS_READ_B128(dst, off) \
    asm volatile("ds_read_b128 %0, %1" : "=v"(dst) : "v"(off))

// ---------------- split fp32 array (len % 1024 == 0) into hi/lo fp16 planes ----
__global__ __launch_bounds__(256) void split2h(const float* __restrict__ X,
                                               u16* __restrict__ H,
                                               u16* __restrict__ L) {
    const int idx = (blockIdx.x * 256 + threadIdx.x) * 4;
    float4 x = *(const float4*)&X[idx];
    float c[4] = {x.x, x.y, x.z, x.w};
    u16 h[4], l[4];
#pragma unroll
    for (int i = 0; i < 4; ++i) {
        _Float16 hh = (_Float16)c[i];
        float r = c[i] - (float)hh;
        _Float16 ll = (_Float16)r;
        h[i] = *(u16*)&hh; l[i] = *(u16*)&ll;
    }
    *(ushort4*)&H[idx] = make_ushort4(h[0], h[1], h[2], h[3]);
    *(ushort4*)&L[idx] = make_ushort4(l[0], l[1], l[2], l[3]);
}

// ---------------- transpose Wv, keep hi fp16 plane: Wvth[c][d] = f16(Wv[d][c]) -
__global__ __launch_bounds__(256) void split_wvt(const float* __restrict__ W,
                                                 u16* __restrict__ H) {
    __shared__ float t[64][65];
    const int k0 = blockIdx.x * 64, n0 = blockIdx.y * 64;
    const int c = threadIdx.x & 63, r4 = threadIdx.x >> 6;
#pragma unroll
    for (int i = 0; i < 16; ++i) {
        int k = r4 + i * 4;
        t[k][c] = W[(size_t)(k0 + k) * DIM + n0 + c];
    }
    __syncthreads();
#pragma unroll
    for (int i = 0; i < 16; ++i) {
        int n = r4 + i * 4;
        _Float16 hb = (_Float16)t[c][n];
        H[(n0 + n) * DIM + k0 + c] = *(u16*)&hb;
    }
}

// ---------------- OLD 128x128 NT fp16 GEMM engine (g_gemm only, proven) -------
template<int NP>
__device__ __forceinline__ void gemm_lds(const u16* const (&Ap)[NP],
                                         const u16* const (&Bp)[NP],
                                         int row0, int col0, f32x4 (&acc)[4][4],
                                         short (&As)[2][2][4096], short (&Bs)[2][2][4096]) {
    const int tid = threadIdx.x;
    const int w = tid >> 6, lane = tid & 63;
    const int wy = w >> 1, wx = w & 1;
    const int quad = lane >> 4, r16 = lane & 15;

    const int    srow   = w * 32 + (lane >> 2);
    const int    schunk = (lane & 3) * 8;
    const size_t gA0 = (size_t)(row0 + srow) * DIM + schunk;
    const size_t gA1 = gA0 + (size_t)16 * DIM;
    const size_t gB0 = (size_t)(col0 + srow) * DIM + schunk;
    const size_t gB1 = gB0 + (size_t)16 * DIM;
    const int lds0 = (w * 32) * 32;
    const int lds1 = (w * 32 + 16) * 32;

    auto issue = [&](const u16* A, const u16* B, size_t k0, int buf) {
#pragma unroll
        for (int s = 0; s < 2; ++s) {
            const size_t ko = k0 + (size_t)s * 32;
            __builtin_amdgcn_global_load_lds((const AS1 u32*)(A + gA0 + ko), (AS3 u32*)&As[buf][s][lds0], 16, 0, 0);
            __builtin_amdgcn_global_load_lds((const AS1 u32*)(A + gA1 + ko), (AS3 u32*)&As[buf][s][lds1], 16, 0, 0);
            __builtin_amdgcn_global_load_lds((const AS1 u32*)(B + gB0 + ko), (AS3 u32*)&Bs[buf][s][lds0], 16, 0, 0);
            __builtin_amdgcn_global_load_lds((const AS1 u32*)(B + gB1 + ko), (AS3 u32*)&Bs[buf][s][lds1], 16, 0, 0);
        }
    };

    issue(Ap[0], Bp[0], 0, 0);

    int pp = 0;
#pragma unroll
    for (int p = 0; p < NP; ++p) {
        const u16* A = Ap[p];
        const u16* B = Bp[p];
        const u16* An = (p + 1 < NP) ? Ap[p + 1] : A;
        const u16* Bn = (p + 1 < NP) ? Bp[p + 1] : B;
        const bool more = (p + 1 < NP);
        for (int i = 0; i < 16; ++i) {
            __syncthreads();
            const int cur = pp, nxt = pp ^ 1;
            if (i < 15)      issue(A, B, (size_t)(i + 1) * 64, nxt);
            else if (more)   issue(An, Bn, 0, nxt);
#pragma unroll
            for (int s = 0; s < 2; ++s) {
                const short* AsC = As[cur][s];
                const short* BsC = Bs[cur][s];
                f16x8 af[4], bfr[4];
#pragma unroll
                for (int m = 0; m < 4; ++m)
                    af[m] = *(const f16x8*)&AsC[(wy * 64 + m * 16 + r16) * 32 + quad * 8];
#pragma unroll
                for (int n = 0; n < 4; ++n)
                    bfr[n] = *(const f16x8*)&BsC[(wx * 64 + n * 16 + r16) * 32 + quad * 8];
#pragma unroll
                for (int m = 0; m < 4; ++m)
#pragma unroll
                    for (int n = 0; n < 4; ++n)
                        acc[m][n] = __builtin_amdgcn_mfma_f32_16x16x32_f16(af[m], bfr[n], acc[m][n], 0, 0, 0);
            }
            pp ^= 1;
        }
    }
}

// ---------------- 256x256 NT fp16 engine, 8-phase (m201-template port) --------
// BK=64 split into 2 k-halves of 32. LDS = 2 dbuf x 2 khalf x (256 rows x 32 k)
// x {A,B} = 128 KiB. 8 waves (2My x 4Nx), wave C-tile 128x64 = acc[8][4].
// Per K-tile: 4 phases, each {ds_reads (4 or 8 b128) ; stage 1 half (2
// global_load_lds) ; s_barrier ; lgkmcnt(0)+sched_barrier ; setprio(1) 16 MFMA
// setprio(0) ; [vmcnt(8) at ph1/ph3] ; s_barrier}.
//   ph0: A m0-3 k0 + B k0          stage Bk1[t+1]   (region dead since t-1 ph2)
//   ph1: A m4-7 k0 (B reused)      stage Ak1[t+1]   (dead since t-1 ph3)  W1
//   ph2: A m0-3 k1 + B k1          stage Ak0[t+2]   (in-place: dead after ph1)
//   ph3: A m4-7 k1 (B reused)      stage Bk0[t+2]   (in-place: dead after ph0)  W0
// In-place staging is race-free: the stage in phase p issues only after the
// second barrier of phase p-1, and every wave's ds_reads of phase p-1 complete
// before its lgkmcnt(0) -> MFMA -> barrier. Wait derivation (2 loads/stage):
// at W1/W0 exactly 4 stages (8 loads) may legitimately remain in flight ->
// vmcnt(8); tail tiles peeled with vmcnt(4)/vmcnt(0). Never drains mid-loop.
// Source pre-swizzle (proven: conflicts 1.7e7 -> 0) unchanged.
template<int NP>
__device__ __forceinline__ void gemm256(const u16* const (&Ap)[NP],
                                        const u16* const (&Bp)[NP],
                                        int row0, int col0, f32x4 (&acc)[8][4],
                                        short (&As)[2][2][8192], short (&Bs)[2][2][8192]) {
    const int tid = threadIdx.x;
    const int w = tid >> 6, lane = tid & 63;
    const int wy = w >> 2, wx = w & 3;
    const int quad = lane >> 4, r16 = lane & 15;

    // staging map: wave w covers half-rows w*16..w*16+15 (l0) and +128 (l1);
    // LDS dest linear (HW appends lane*16B), global source chunk pre-swizzled.
    const int srow   = w * 16 + (lane >> 2);
    const int schunk = ((lane & 3) ^ ((lane >> 3) & 3)) * 8;
    const size_t gA0 = (size_t)(row0 + srow) * DIM + schunk;
    const size_t gA1 = gA0 + (size_t)128 * DIM;
    const size_t gB0 = (size_t)(col0 + srow) * DIM + schunk;
    const size_t gB1 = gB0 + (size_t)128 * DIM;
    const int l0 = w * 512;            // shorts within one 16 KiB half-region
    const int l1 = 4096 + w * 512;

    // product select without dynamic array indexing (rule #20)
    auto selA = [&](int p) -> const u16* {
        const u16* r = Ap[0];
        if (NP > 1) { if (p == 1) r = Ap[1]; if (p >= 2) r = Ap[NP > 2 ? 2 : 0]; }
        return r;
    };
    auto selB = [&](int p) -> const u16* {
        const u16* r = Bp[0];
        if (NP > 1) { if (p == 1) r = Bp[1]; if (p >= 2) r = Bp[NP > 2 ? 2 : 0]; }
        return r;
    };

    auto stageA = [&](int t, int kh) {
        const u16* A = selA(t >> 4);
        const size_t ko = (size_t)(t & 15) * 64 + (size_t)kh * 32;
        __builtin_amdgcn_global_load_lds((const AS1 u32*)(A + gA0 + ko), (AS3 u32*)&As[t & 1][kh][l0], 16, 0, 0);
        __builtin_amdgcn_global_load_lds((const AS1 u32*)(A + gA1 + ko), (AS3 u32*)&As[t & 1][kh][l1], 16, 0, 0);
    };
    auto stageB = [&](int t, int kh) {
        const u16* B = selB(t >> 4);
        const size_t ko = (size_t)(t & 15) * 64 + (size_t)kh * 32;
        __builtin_amdgcn_global_load_lds((const AS1 u32*)(B + gB0 + ko), (AS3 u32*)&Bs[t & 1][kh][l0], 16, 0, 0);
        __builtin_amdgcn_global_load_lds((const AS1 u32*)(B + gB1 + ko), (AS3 u32*)&Bs[t & 1][kh][l1], 16, 0, 0);
    };

    // read-side swizzled LDS byte offsets (buf 0, khalf 0)
    const int ccol = (quad ^ ((r16 >> 1) & 3)) * 8;
    u32 aAb[8], aBb[4];
#pragma unroll
    for (int m = 0; m < 8; ++m)
        aAb[m] = (u32)(uintptr_t)&As[0][0][(wy * 128 + m * 16 + r16) * 32 + ccol];
#pragma unroll
    for (int n = 0; n < 4; ++n)
        aBb[n] = (u32)(uintptr_t)&Bs[0][0][(wx * 64 + n * 16 + r16) * 32 + ccol];

    f16x8 af[4], bf[4];

#define PH(KH, MBASE, LOADB, STAGE_STMT, WAIT_ASM) do {                          \
        const u32 _o = bo + (u32)(KH) * 16384u;                                  \
        _Pragma("unroll")                                                        \
        for (int _m = 0; _m < 4; ++_m) DS_READ_B128(af[_m], aAb[(MBASE) + _m] + _o); \
        if (LOADB) {                                                             \
            _Pragma("unroll")                                                    \
            for (int _n = 0; _n < 4; ++_n) DS_READ_B128(bf[_n], aBb[_n] + _o);   \
        }                                                                        \
        STAGE_STMT;                                                              \
        __builtin_amdgcn_s_barrier();                                            \
        asm volatile("s_waitcnt lgkmcnt(0)");                                    \
        __builtin_amdgcn_sched_barrier(0);                                       \
        __builtin_amdgcn_s_setprio(1);                                           \
        _Pragma("unroll")                                                        \
        for (int _m = 0; _m < 4; ++_m)                                           \
            _Pragma("unroll")                                                    \
            for (int _n = 0; _n < 4; ++_n)                                       \
                acc[(MBASE) + _m][_n] = __builtin_amdgcn_mfma_f32_16x16x32_f16(  \
                    af[_m], bf[_n], acc[(MBASE) + _m][_n], 0, 0, 0);             \
        __builtin_amdgcn_s_setprio(0);                                           \
        __builtin_amdgcn_sched_barrier(0);                                       \
        asm volatile(WAIT_ASM);                                                  \
        __builtin_amdgcn_s_barrier();                                            \
    } while (0)

#define TILE(T, S01, S23, W1S, W0S) do {                                         \
        const u32 bo = (u32)((T) & 1) * 32768u;                                  \
        PH(0, 0, true,  { if (S01) stageB((T) + 1, 1); }, "");                   \
        PH(0, 4, false, { if (S01) stageA((T) + 1, 1); }, W1S);                  \
        PH(1, 0, true,  { if (S23) stageA((T) + 2, 0); }, "");                   \
        PH(1, 4, false, { if (S23) stageB((T) + 2, 0); }, W0S);                  \
    } while (0)

    constexpr int NT = NP * 16;
    // prologue: Ak0[0],Bk0[0],Ak1[0],Bk1[0],Ak0[1],Bk0[1]; wait oldest 2 stages
    stageA(0, 0); stageB(0, 0); stageA(0, 1); stageB(0, 1);
    stageA(1, 0); stageB(1, 0);
    asm volatile("s_waitcnt vmcnt(8)");
    __builtin_amdgcn_s_barrier();

#pragma unroll 1
    for (int t = 0; t < NT - 2; ++t)
        TILE(t, true, true, "s_waitcnt vmcnt(8)", "s_waitcnt vmcnt(8)");
    TILE(NT - 2, true, false, "s_waitcnt vmcnt(8)", "s_waitcnt vmcnt(4)");
    TILE(NT - 1, false, false, "s_waitcnt vmcnt(0)", "");

#undef TILE
#undef PH
}

// ---------------- Gt = Wk @ Wq^T (fp32 out, Gt[c][d] = (Wq Wk^T)[d][c]) --------
__global__ __launch_bounds__(256) void g_gemm(const u16* __restrict__ Wkh, const u16* __restrict__ Wkl,
                                              const u16* __restrict__ Wqh, const u16* __restrict__ Wql,
                                              float* __restrict__ Gt) {
    __shared__ short As[2][2][4096], Bs[2][2][4096];
    const int tid = threadIdx.x, w = tid >> 6, lane = tid & 63;
    const int wy = w >> 1, wx = w & 1, quad = lane >> 4, r16 = lane & 15;
    const int row0 = blockIdx.y * 128, col0 = blockIdx.x * 128;
    const u16* const Ap[3] = { Wkl, Wkh, Wkh };   // lh, hl, hh (small -> large)
    const u16* const Bp[3] = { Wqh, Wql, Wqh };
    f32x4 acc[4][4] = {};
    gemm_lds<3>(Ap, Bp, row0, col0, acc, As, Bs);
#pragma unroll
    for (int m = 0; m < 4; ++m)
#pragma unroll
        for (int n = 0; n < 4; ++n)
#pragma unroll
            for (int reg = 0; reg < 4; ++reg) {
                const int row = row0 + wy * 64 + m * 16 + quad * 4 + reg;
                const int col = col0 + wx * 64 + n * 16 + r16;
                Gt[row * DIM + col] = acc[m][n][reg];
            }
}

// ---------------- part0: Y = X@G (fp32+fp16) ; part1: Vh = Xh@Wvt_h -----------
__global__ __launch_bounds__(512, 2) void yv_gemm(const u16* __restrict__ Xh, const u16* __restrict__ Xl,
                                                  const u16* __restrict__ Gth, const u16* __restrict__ Gtl,
                                                  const u16* __restrict__ Wvth,
                                                  float* __restrict__ Y, u16* __restrict__ Yh, u16* __restrict__ Vh) {
    __shared__ short As[2][2][8192], Bs[2][2][8192];
    const int tid = threadIdx.x, w = tid >> 6, lane = tid & 63;
    const int wy = w >> 2, wx = w & 3, quad = lane >> 4, r16 = lane & 15;
    const int id = blockIdx.x;
    const int part = id >> 7;              // 0: Y (K_eff=3072), 1: V (K=1024)
    const int within = id & 127;
    const int rowt = within >> 2, colt = within & 3;
    const int row0 = rowt * 256, col0 = colt * 256;
    f32x4 acc[8][4] = {};
    if (part == 0) {
        const u16* const Ap[3] = { Xl,  Xh,  Xh  };   // lh, hl, hh
        const u16* const Bp[3] = { Gth, Gtl, Gth };
        gemm256<3>(Ap, Bp, row0, col0, acc, As, Bs);
#pragma unroll
        for (int m = 0; m < 8; ++m)
#pragma unroll
            for (int n = 0; n < 4; ++n)
#pragma unroll
                for (int reg = 0; reg < 4; ++reg) {
                    const int row = row0 + wy * 128 + m * 16 + quad * 4 + reg;
                    const int col = col0 + wx * 64 + n * 16 + r16;
                    float v = acc[m][n][reg];
                    Y[(size_t)row * DIM + col] = v;
                    _Float16 hb = (_Float16)v;
                    Yh[(size_t)row * DIM + col] = *(u16*)&hb;
                }
    } else {
        const u16* const Ap[1] = { Xh };
        const u16* const Bp[1] = { Wvth };
        gemm256<1>(Ap, Bp, row0, col0, acc, As, Bs);
#pragma unroll
        for (int m = 0; m < 8; ++m)
#pragma unroll
            for (int n = 0; n < 4; ++n)
#pragma unroll
                for (int reg = 0; reg < 4; ++reg) {
                    const int row = row0 + wy * 128 + m * 16 + quad * 4 + reg;
                    const int col = col0 + wx * 64 + n * 16 + r16;
                    _Float16 hb = (_Float16)acc[m][n][reg];
                    Vh[(size_t)row * DIM + col] = *(u16*)&hb;
                }
    }
}

// ---------------- filter: S = Yh @ Xh^T (fp16), per-64col-group margin emit ----
__global__ __launch_bounds__(512, 2) void filter_kernel(const u16* __restrict__ Yhp,
                                                        const u16* __restrict__ Xhp,
                                                        int* __restrict__ cnt,
                                                        int2* __restrict__ cand) {
    __shared__ short As[2][2][8192], Bs[2][2][8192];
    const int tid = threadIdx.x, w = tid >> 6, lane = tid & 63;
    const int wy = w >> 2, wx = w & 3, quad = lane >> 4, r16 = lane & 15;
    const int id = blockIdx.x;
    const int xcd = id & 7, within = id >> 3;
    const int colt = (xcd << 2) | (within & 3);   // 0..31, 4 per XCD
    const int rowt = within >> 2;                  // 0..31
    const int row0 = rowt << 8, col0 = colt << 8;

    const u16* const Ap[1] = { Yhp };
    const u16* const Bp[1] = { Xhp };
    f32x4 acc[8][4] = {};
    gemm256<1>(Ap, Bp, row0, col0, acc, As, Bs);

    // per row: 64-col group max -> margin filter -> emit (mechanics proven)
#pragma unroll
    for (int m = 0; m < 8; ++m) {
#pragma unroll
        for (int reg = 0; reg < 4; ++reg) {
            float mx = fmaxf(fmaxf(acc[m][0][reg], acc[m][1][reg]),
                             fmaxf(acc[m][2][reg], acc[m][3][reg]));
            mx = fmaxf(mx, __shfl_xor(mx, 1, 64));
            mx = fmaxf(mx, __shfl_xor(mx, 2, 64));
            mx = fmaxf(mx, __shfl_xor(mx, 4, 64));
            mx = fmaxf(mx, __shfl_xor(mx, 8, 64));
            const float th = mx - MARGIN;
            const int row = row0 + wy * 128 + m * 16 + quad * 4 + reg;
#pragma unroll
            for (int n = 0; n < 4; ++n) {
                float s = acc[m][n][reg];
                if (s >= th) {
                    int pos = atomicAdd(&cnt[row], 1);
                    if (pos < CAP)
                        cand[(size_t)row * CAP + pos] =
                            make_int2(col0 + wx * 64 + n * 16 + r16, __float_as_int(s));
                }
            }
        }
    }
}

// ---------------- finalize: refilter, fp64 rescore via Y·X, softmax, gather Vh -
__global__ __launch_bounds__(256) void finalize_kernel(const float* __restrict__ Y,
                                                       const float* __restrict__ X,
                                                       const u16* __restrict__ Vh,
                                                       const int* __restrict__ cnt,
                                                       const int2* __restrict__ cand,
                                                       float* __restrict__ out) {
    const int i = blockIdx.x;
    const int tid = threadIdx.x;
    const int w = tid >> 6, lane = tid & 63;
    __shared__ float  red[256];
    __shared__ int    surv[64];
    __shared__ double sprec[64];
    __shared__ float  wgt[64];
    __shared__ int    nsurv;

    const int c = min(cnt[i], CAP);
    float m = -3.0e38f;
    for (int t = tid; t < c; t += 256)
        m = fmaxf(m, __int_as_float(cand[(size_t)i * CAP + t].y));
    red[tid] = m;
    __syncthreads();
    for (int s = 128; s > 0; s >>= 1) {
        if (tid < s) red[tid] = fmaxf(red[tid], red[tid + s]);
        __syncthreads();
    }
    const float th = red[0] - MARGIN;
    if (tid == 0) nsurv = 0;
    __syncthreads();
    for (int t = tid; t < c; t += 256) {
        int2 e = cand[(size_t)i * CAP + t];
        if (__int_as_float(e.y) >= th) {
            int p = atomicAdd(&nsurv, 1);
            if (p < 64) surv[p] = e.x;
        }
    }
    __syncthreads();
    const int ns = min(nsurv, 64);
    for (int u = w; u < ns; u += 4) {
        const int j = surv[u];
        double a = 0.0;
        for (int d = lane; d < DIM; d += 64)
            a += (double)Y[(size_t)i * DIM + d] * (double)X[(size_t)j * DIM + d];
#pragma unroll
        for (int o = 32; o > 0; o >>= 1)
            a += __shfl_down(a, o, 64);
        if (lane == 0) sprec[u] = a;
    }
    __syncthreads();
    if (tid == 0) {
        double mm = -1.0e300;
        for (int u = 0; u < ns; ++u) mm = fmax(mm, sprec[u]);
        double l = 0.0;
        for (int u = 0; u < ns; ++u) l += exp(sprec[u] - mm);
        for (int u = 0; u < ns; ++u) wgt[u] = (float)(exp(sprec[u] - mm) / l);
    }
    __syncthreads();
    for (int d = tid; d < DIM; d += 256) {
        float o = 0.f;
        for (int u = 0; u < ns; ++u) {
            _Float16 hv = *(const _Float16*)&Vh[(size_t)surv[u] * DIM + d];
            o += wgt[u] * (float)hv;
        }
        out[(size_t)i * DIM + d] = o;
    }
}

extern "C" void kernel_launch(void* const* d_in, const int* in_sizes, int n_in,
                              void* d_out, int out_size, void* d_ws, size_t ws_size,
                              hipStream_t stream) {
    const float* X  = (const float*)d_in[0];
    const float* wq = (const float*)d_in[1];
    const float* wk = (const float*)d_in[2];
    const float* wv = (const float*)d_in[3];
    float* out = (float*)d_out;

    char* ws = (char*)d_ws;
    const size_t MB = 1024 * 1024;
    u16*   Xh   = (u16*)(ws +   0 * MB);   // 16 MB
    u16*   Xl   = (u16*)(ws +  16 * MB);   // 16 MB
    u16*   Wqh  = (u16*)(ws +  32 * MB);   // 2 MB each
    u16*   Wql  = (u16*)(ws +  34 * MB);
    u16*   Wkh  = (u16*)(ws +  36 * MB);
    u16*   Wkl  = (u16*)(ws +  38 * MB);
    u16*   Wvth = (u16*)(ws +  40 * MB);
    float* Gt   = (float*)(ws + 42 * MB);  // 4 MB fp32 [c][d]
    u16*   Gth  = (u16*)(ws +  46 * MB);
    u16*   Gtl  = (u16*)(ws +  48 * MB);
    float* Y    = (float*)(ws + 64 * MB);  // 32 MB
    u16*   Yh   = (u16*)(ws +  96 * MB);   // 16 MB
    u16*   Vh   = (u16*)(ws + 112 * MB);   // 16 MB
    int*   cnt  = (int*)(ws + 128 * MB);   // 32 KB
    int2*  cand = (int2*)(ws + 129 * MB);  // 8192*256*8 = 16.8 MB

    hipMemsetAsync(cnt, 0, (size_t)NROWS * 4, stream);

    split2h<<<NROWS * DIM / 1024, 256, 0, stream>>>(X, Xh, Xl);
    split2h<<<DIM * DIM / 1024, 256, 0, stream>>>(wq, Wqh, Wql);
    split2h<<<DIM * DIM / 1024, 256, 0, stream>>>(wk, Wkh, Wkl);
    split_wvt<<<dim3(16, 16), 256, 0, stream>>>(wv, Wvth);

    g_gemm<<<dim3(8, 8), 256, 0, stream>>>(Wkh, Wkl, Wqh, Wql, Gt);
    split2h<<<DIM * DIM / 1024, 256, 0, stream>>>(Gt, Gth, Gtl);

    yv_gemm<<<256, 512, 0, stream>>>(Xh, Xl, Gth, Gtl, Wvth, Y, Yh, Vh);

    filter_kernel<<<1024, 512, 0, stream>>>(Yh, Xh, cnt, cand);

    finalize_kernel<<<NROWS, 256, 0, stream>>>(Y, X, Vh, cnt, cand, out);
}

// Round 4
// 533.362 us; speedup vs baseline: 1.2365x; 1.2365x over previous
//
#include <hip/hip_runtime.h>
#include <hip/hip_bf16.h>
#include <math.h>

#define NROWS 8192
#define DIM   1024
#define CAP   256
#define MARGIN 120.0f

using f16x8 = __attribute__((ext_vector_type(8))) _Float16;
using f32x4 = __attribute__((ext_vector_type(4))) float;
typedef unsigned short u16;
typedef unsigned int   u32;

#define AS1 __attribute__((address_space(1)))
#define AS3 __attribute__((address_space(3)))

// ---------------- split fp32 array (len % 1024 == 0) into hi/lo fp16 planes ----
// fp16 2-split carries ~22 mantissa bits: hi + lo with lo = fp16(x - (float)hi).
__global__ __launch_bounds__(256) void split2h(const float* __restrict__ X,
                                               u16* __restrict__ H,
                                               u16* __restrict__ L) {
    const int idx = (blockIdx.x * 256 + threadIdx.x) * 4;
    float4 x = *(const float4*)&X[idx];
    float c[4] = {x.x, x.y, x.z, x.w};
    u16 h[4], l[4];
#pragma unroll
    for (int i = 0; i < 4; ++i) {
        _Float16 hh = (_Float16)c[i];
        float r = c[i] - (float)hh;
        _Float16 ll = (_Float16)r;
        h[i] = *(u16*)&hh; l[i] = *(u16*)&ll;
    }
    *(ushort4*)&H[idx] = make_ushort4(h[0], h[1], h[2], h[3]);
    *(ushort4*)&L[idx] = make_ushort4(l[0], l[1], l[2], l[3]);
}

// ---------------- transpose Wv, keep hi fp16 plane: Wvth[c][d] = f16(Wv[d][c]) -
__global__ __launch_bounds__(256) void split_wvt(const float* __restrict__ W,
                                                 u16* __restrict__ H) {
    __shared__ float t[64][65];
    const int k0 = blockIdx.x * 64, n0 = blockIdx.y * 64;
    const int c = threadIdx.x & 63, r4 = threadIdx.x >> 6;
#pragma unroll
    for (int i = 0; i < 16; ++i) {
        int k = r4 + i * 4;
        t[k][c] = W[(size_t)(k0 + k) * DIM + n0 + c];
    }
    __syncthreads();
#pragma unroll
    for (int i = 0; i < 16; ++i) {
        int n = r4 + i * 4;
        _Float16 hb = (_Float16)t[c][n];
        H[(n0 + n) * DIM + k0 + c] = *(u16*)&hb;
    }
}

// ---------------- shared LDS-dbuf 128x128 NT fp16 GEMM engine, BK=32 -----------
// m97-regime revert (R1-R3 post-mortem): the 2-barrier __syncthreads loop at
// 32 KiB LDS runs 4-5 blocks/CU; cross-block TLP hides the barrier's vmcnt
// drain (m114 mechanism, measured 912 TF @4k / 898 @8k for this structure).
// BK=64 (64 KiB) halves occupancy and loses ~1.8x (m132: 912->508); the three
// 1-block/CU 256^2 schedules of R1-R3 all landed at ~330 TF regardless of
// pipelining sophistication -- occupancy, not schedule, is the lever here.
// Bank-conflict swizzle (verified R1: SQ_LDS_BANK_CONFLICT 1.68e7 -> 0):
// global source chunk pre-swizzled (lane&3)^((lane>>3)&3) so LDS slot c holds
// chunk c^((row>>1)&3); read side uses col (quad^((r16>>1)&3))*8. Valid for
// all m/wy since (m*16+wy*64)>>1 == 0 mod 4. 16-lane read phases then spread
// 2 lanes/bank (free, m136) instead of 8-way.
template<int NP>
__device__ __forceinline__ void gemm_lds(const u16* const (&Ap)[NP],
                                         const u16* const (&Bp)[NP],
                                         int row0, int col0, f32x4 (&acc)[4][4],
                                         short (&As)[2][4096], short (&Bs)[2][4096]) {
    const int tid = threadIdx.x;
    const int w = tid >> 6, lane = tid & 63;
    const int wy = w >> 1, wx = w & 1;
    const int quad = lane >> 4, r16 = lane & 15;

    // staging map: lane l covers tile row w*32 + (l>>2) (+16 for the second
    // instruction), source 16B chunk pre-swizzled; HW appends lane*16B to the
    // wave-uniform LDS base -> row-major [row][32 shorts], slot = lane&3.
    const int    srow   = w * 32 + (lane >> 2);
    const int    schunk = ((lane & 3) ^ ((lane >> 3) & 3)) * 8;
    const size_t gA0 = (size_t)(row0 + srow) * DIM + schunk;
    const size_t gA1 = gA0 + (size_t)16 * DIM;
    const size_t gB0 = (size_t)(col0 + srow) * DIM + schunk;
    const size_t gB1 = gB0 + (size_t)16 * DIM;
    const int lds0 = (w * 32) * 32;
    const int lds1 = (w * 32 + 16) * 32;

    auto issue = [&](const u16* A, const u16* B, size_t ko, int buf) {
        __builtin_amdgcn_global_load_lds((const AS1 u32*)(A + gA0 + ko), (AS3 u32*)&As[buf][lds0], 16, 0, 0);
        __builtin_amdgcn_global_load_lds((const AS1 u32*)(A + gA1 + ko), (AS3 u32*)&As[buf][lds1], 16, 0, 0);
        __builtin_amdgcn_global_load_lds((const AS1 u32*)(B + gB0 + ko), (AS3 u32*)&Bs[buf][lds0], 16, 0, 0);
        __builtin_amdgcn_global_load_lds((const AS1 u32*)(B + gB1 + ko), (AS3 u32*)&Bs[buf][lds1], 16, 0, 0);
    };

    issue(Ap[0], Bp[0], 0, 0);             // preload product 0, k-chunk 0

    const int ccol = (quad ^ ((r16 >> 1) & 3)) * 8;   // swizzled read column

    int pp = 0;
#pragma unroll
    for (int p = 0; p < NP; ++p) {
        const u16* A = Ap[p];
        const u16* B = Bp[p];
        const u16* An = (p + 1 < NP) ? Ap[p + 1] : A;
        const u16* Bn = (p + 1 < NP) ? Bp[p + 1] : B;
        const bool more = (p + 1 < NP);
        for (int i = 0; i < 32; ++i) {     // K/32 iterations
            __syncthreads();               // loads for this iter complete; prior ds_reads done
            const int cur = pp, nxt = pp ^ 1;
            if (i < 31)      issue(A, B, (size_t)(i + 1) * 32, nxt);
            else if (more)   issue(An, Bn, 0, nxt);
            const short* AsC = As[cur];
            const short* BsC = Bs[cur];
            f16x8 af[4], bfr[4];
#pragma unroll
            for (int m = 0; m < 4; ++m)
                af[m] = *(const f16x8*)&AsC[(wy * 64 + m * 16 + r16) * 32 + ccol];
#pragma unroll
            for (int n = 0; n < 4; ++n)
                bfr[n] = *(const f16x8*)&BsC[(wx * 64 + n * 16 + r16) * 32 + ccol];
#pragma unroll
            for (int m = 0; m < 4; ++m)
#pragma unroll
                for (int n = 0; n < 4; ++n)
                    acc[m][n] = __builtin_amdgcn_mfma_f32_16x16x32_f16(af[m], bfr[n], acc[m][n], 0, 0, 0);
            pp ^= 1;
        }
    }
}

// ---------------- Gt = Wk @ Wq^T (fp32 out, Gt[c][d] = (Wq Wk^T)[d][c]) --------
// fp16 2-split: 3 products {lh, hl, hh} carry ~22 bits (ll dropped, rel 2^-22).
__global__ __launch_bounds__(256) void g_gemm(const u16* __restrict__ Wkh, const u16* __restrict__ Wkl,
                                              const u16* __restrict__ Wqh, const u16* __restrict__ Wql,
                                              float* __restrict__ Gt) {
    __shared__ short As[2][4096], Bs[2][4096];
    const int tid = threadIdx.x, w = tid >> 6, lane = tid & 63;
    const int wy = w >> 1, wx = w & 1, quad = lane >> 4, r16 = lane & 15;
    const int row0 = blockIdx.y * 128, col0 = blockIdx.x * 128;
    const u16* const Ap[3] = { Wkl, Wkh, Wkh };   // lh, hl, hh (small -> large)
    const u16* const Bp[3] = { Wqh, Wql, Wqh };
    f32x4 acc[4][4] = {};
    gemm_lds<3>(Ap, Bp, row0, col0, acc, As, Bs);
#pragma unroll
    for (int m = 0; m < 4; ++m)
#pragma unroll
        for (int n = 0; n < 4; ++n)
#pragma unroll
            for (int reg = 0; reg < 4; ++reg) {
                const int row = row0 + wy * 64 + m * 16 + quad * 4 + reg;
                const int col = col0 + wx * 64 + n * 16 + r16;
                Gt[row * DIM + col] = acc[m][n][reg];
            }
}

// ---------------- id<512: Y = X@G (fp32+fp16) ; id>=512: Vh = Xh@Wvt_h ---------
// id = z*512 + colt*64 + rowt -> id%8 == rowt%8: XCD round-robin pins each
// XCD's 8 A-row-tiles in its L2 (proven: FETCH 918 -> 87 MB class of fix).
__global__ __launch_bounds__(256) void yv_gemm(const u16* __restrict__ Xh, const u16* __restrict__ Xl,
                                               const u16* __restrict__ Gth, const u16* __restrict__ Gtl,
                                               const u16* __restrict__ Wvth,
                                               float* __restrict__ Y, u16* __restrict__ Yh, u16* __restrict__ Vh) {
    __shared__ short As[2][4096], Bs[2][4096];
    const int tid = threadIdx.x, w = tid >> 6, lane = tid & 63;
    const int wy = w >> 1, wx = w & 1, quad = lane >> 4, r16 = lane & 15;
    const int id = blockIdx.x;
    const int z = id >> 9;
    const int within = id & 511;
    const int colt = within >> 6;          // 0..7
    const int rowt = within & 63;          // 0..63
    const int row0 = rowt * 128, col0 = colt * 128;
    f32x4 acc[4][4] = {};
    if (z == 0) {
        const u16* const Ap[3] = { Xl,  Xh,  Xh  };   // lh, hl, hh
        const u16* const Bp[3] = { Gth, Gtl, Gth };
        gemm_lds<3>(Ap, Bp, row0, col0, acc, As, Bs);
#pragma unroll
        for (int m = 0; m < 4; ++m)
#pragma unroll
            for (int n = 0; n < 4; ++n)
#pragma unroll
                for (int reg = 0; reg < 4; ++reg) {
                    const int row = row0 + wy * 64 + m * 16 + quad * 4 + reg;
                    const int col = col0 + wx * 64 + n * 16 + r16;
                    float v = acc[m][n][reg];
                    Y[row * DIM + col] = v;
                    _Float16 hb = (_Float16)v;
                    Yh[row * DIM + col] = *(u16*)&hb;
                }
    } else {
        const u16* const Ap[1] = { Xh };
        const u16* const Bp[1] = { Wvth };
        gemm_lds<1>(Ap, Bp, row0, col0, acc, As, Bs);
#pragma unroll
        for (int m = 0; m < 4; ++m)
#pragma unroll
            for (int n = 0; n < 4; ++n)
#pragma unroll
                for (int reg = 0; reg < 4; ++reg) {
                    const int row = row0 + wy * 64 + m * 16 + quad * 4 + reg;
                    const int col = col0 + wx * 64 + n * 16 + r16;
                    _Float16 hb = (_Float16)acc[m][n][reg];
                    Vh[row * DIM + col] = *(u16*)&hb;
                }
    }
}

// ---------------- filter: S = Yh @ Xh^T (fp16), per-64col-group margin emit ----
// fp16 score error sigma ~ 10 -> MARGIN 120 (>9 sigma slack over the e^-30
// relevance window). Group max is always emitted, so the global argmax and any
// same/other-group runner-up always survive.
__global__ __launch_bounds__(256) void filter_kernel(const u16* __restrict__ Yhp,
                                                     const u16* __restrict__ Xhp,
                                                     int* __restrict__ cnt,
                                                     int2* __restrict__ cand) {
    __shared__ short As[2][4096], Bs[2][4096];
    const int tid = threadIdx.x, w = tid >> 6, lane = tid & 63;
    const int wy = w >> 1, wx = w & 1, quad = lane >> 4, r16 = lane & 15;
    const int id = blockIdx.x;
    const int colt = id >> 6;              // 0..63 ; id%8 == rowt%8 (XCD pin)
    const int rowt = id & 63;              // 0..63
    const int row0 = rowt * 128, col0 = colt * 128;

    const u16* const Ap[1] = { Yhp };
    const u16* const Bp[1] = { Xhp };
    f32x4 acc[4][4] = {};
    gemm_lds<1>(Ap, Bp, row0, col0, acc, As, Bs);

    // per row: 64-col group max -> margin filter -> emit (mechanics proven)
#pragma unroll
    for (int m = 0; m < 4; ++m) {
#pragma unroll
        for (int reg = 0; reg < 4; ++reg) {
            float mx = fmaxf(fmaxf(acc[m][0][reg], acc[m][1][reg]),
                             fmaxf(acc[m][2][reg], acc[m][3][reg]));
            mx = fmaxf(mx, __shfl_xor(mx, 1, 64));
            mx = fmaxf(mx, __shfl_xor(mx, 2, 64));
            mx = fmaxf(mx, __shfl_xor(mx, 4, 64));
            mx = fmaxf(mx, __shfl_xor(mx, 8, 64));
            const float th = mx - MARGIN;
            const int row = row0 + wy * 64 + m * 16 + quad * 4 + reg;
#pragma unroll
            for (int n = 0; n < 4; ++n) {
                float s = acc[m][n][reg];
                if (s >= th) {
                    int pos = atomicAdd(&cnt[row], 1);
                    if (pos < CAP)
                        cand[(size_t)row * CAP + pos] =
                            make_int2(col0 + wx * 64 + n * 16 + r16, __float_as_int(s));
                }
            }
        }
    }
}

// ---------------- finalize: refilter, fp64 rescore via Y·X, softmax, gather Vh -
__global__ __launch_bounds__(256) void finalize_kernel(const float* __restrict__ Y,
                                                       const float* __restrict__ X,
                                                       const u16* __restrict__ Vh,
                                                       const int* __restrict__ cnt,
                                                       const int2* __restrict__ cand,
                                                       float* __restrict__ out) {
    const int i = blockIdx.x;
    const int tid = threadIdx.x;
    const int w = tid >> 6, lane = tid & 63;
    __shared__ float  red[256];
    __shared__ int    surv[64];
    __shared__ double sprec[64];
    __shared__ float  wgt[64];
    __shared__ int    nsurv;

    const int c = min(cnt[i], CAP);
    float m = -3.0e38f;
    for (int t = tid; t < c; t += 256)
        m = fmaxf(m, __int_as_float(cand[(size_t)i * CAP + t].y));
    red[tid] = m;
    __syncthreads();
    for (int s = 128; s > 0; s >>= 1) {
        if (tid < s) red[tid] = fmaxf(red[tid], red[tid + s]);
        __syncthreads();
    }
    const float th = red[0] - MARGIN;
    if (tid == 0) nsurv = 0;
    __syncthreads();
    for (int t = tid; t < c; t += 256) {
        int2 e = cand[(size_t)i * CAP + t];
        if (__int_as_float(e.y) >= th) {
            int p = atomicAdd(&nsurv, 1);
            if (p < 64) surv[p] = e.x;
        }
    }
    __syncthreads();
    const int ns = min(nsurv, 64);
    // fp64 rescore: s_ij = y_i . x_j (exact given fp32 Y), one survivor per wave
    for (int u = w; u < ns; u += 4) {
        const int j = surv[u];
        double a = 0.0;
        for (int d = lane; d < DIM; d += 64)
            a += (double)Y[(size_t)i * DIM + d] * (double)X[(size_t)j * DIM + d];
#pragma unroll
        for (int o = 32; o > 0; o >>= 1)
            a += __shfl_down(a, o, 64);
        if (lane == 0) sprec[u] = a;
    }
    __syncthreads();
    if (tid == 0) {
        double mm = -1.0e300;
        for (int u = 0; u < ns; ++u) mm = fmax(mm, sprec[u]);
        double l = 0.0;
        for (int u = 0; u < ns; ++u) l += exp(sprec[u] - mm);
        for (int u = 0; u < ns; ++u) wgt[u] = (float)(exp(sprec[u] - mm) / l);
    }
    __syncthreads();
    for (int d = tid; d < DIM; d += 256) {
        float o = 0.f;
        for (int u = 0; u < ns; ++u) {
            _Float16 hv = *(const _Float16*)&Vh[(size_t)surv[u] * DIM + d];
            o += wgt[u] * (float)hv;
        }
        out[(size_t)i * DIM + d] = o;
    }
}

extern "C" void kernel_launch(void* const* d_in, const int* in_sizes, int n_in,
                              void* d_out, int out_size, void* d_ws, size_t ws_size,
                              hipStream_t stream) {
    const float* X  = (const float*)d_in[0];
    const float* wq = (const float*)d_in[1];
    const float* wk = (const float*)d_in[2];
    const float* wv = (const float*)d_in[3];
    float* out = (float*)d_out;

    char* ws = (char*)d_ws;
    const size_t MB = 1024 * 1024;
    u16*   Xh   = (u16*)(ws +   0 * MB);   // 16 MB
    u16*   Xl   = (u16*)(ws +  16 * MB);   // 16 MB
    u16*   Wqh  = (u16*)(ws +  32 * MB);   // 2 MB each
    u16*   Wql  = (u16*)(ws +  34 * MB);
    u16*   Wkh  = (u16*)(ws +  36 * MB);
    u16*   Wkl  = (u16*)(ws +  38 * MB);
    u16*   Wvth = (u16*)(ws +  40 * MB);
    float* Gt   = (float*)(ws + 42 * MB);  // 4 MB fp32 [c][d]
    u16*   Gth  = (u16*)(ws +  46 * MB);
    u16*   Gtl  = (u16*)(ws +  48 * MB);
    float* Y    = (float*)(ws + 64 * MB);  // 32 MB
    u16*   Yh   = (u16*)(ws +  96 * MB);   // 16 MB
    u16*   Vh   = (u16*)(ws + 112 * MB);   // 16 MB
    int*   cnt  = (int*)(ws + 128 * MB);   // 32 KB
    int2*  cand = (int2*)(ws + 129 * MB);  // 8192*256*8 = 16.8 MB

    hipMemsetAsync(cnt, 0, (size_t)NROWS * 4, stream);

    split2h<<<NROWS * DIM / 1024, 256, 0, stream>>>(X, Xh, Xl);
    split2h<<<DIM * DIM / 1024, 256, 0, stream>>>(wq, Wqh, Wql);
    split2h<<<DIM * DIM / 1024, 256, 0, stream>>>(wk, Wkh, Wkl);
    split_wvt<<<dim3(16, 16), 256, 0, stream>>>(wv, Wvth);

    g_gemm<<<dim3(8, 8), 256, 0, stream>>>(Wkh, Wkl, Wqh, Wql, Gt);
    split2h<<<DIM * DIM / 1024, 256, 0, stream>>>(Gt, Gth, Gtl);

    yv_gemm<<<1024, 256, 0, stream>>>(Xh, Xl, Gth, Gtl, Wvth, Y, Yh, Vh);

    filter_kernel<<<4096, 256, 0, stream>>>(Yh, Xh, cnt, cand);

    finalize_kernel<<<NROWS, 256, 0, stream>>>(Y, X, Vh, cnt, cand, out);
}